// Round 3
// baseline (353.908 us; speedup 1.0000x reference)
//
#include <hip/hip_runtime.h>

#define SEQ   512
#define BATCH 16
#define EMB   512
#define NH    8
#define DQ    32
#define DP    4
#define OP    544     // (32+32+4)*8
#define NREL  1023    // 2*SEQ-1

typedef _Float16 f16;
typedef _Float16 f16x4 __attribute__((ext_vector_type(4)));
typedef _Float16 f16x8 __attribute__((ext_vector_type(8)));
typedef float    f32x4 __attribute__((ext_vector_type(4)));

// ---------------- K1: in_proj GEMM via fp16 MFMA ----------------
// proj[m][o] = sum_e x[m][e] * W[o][e] + bias[o];  M=8192, N=544, K=512
// BM=128, BN=64, BK=64; 256 threads = 4 waves in 2x2 wave grid.
// A,B staged fp32->f16 into LDS (row stride 72 f16 = 144B -> balanced
// ds_read_b128 span groups, 8 words/bank). MFMA 16x16x32_f16, fp32 accum.
__global__ __launch_bounds__(256) void k_inproj_mfma(const float* __restrict__ x,
                                                     const float* __restrict__ W,
                                                     const float* __restrict__ bias,
                                                     float* __restrict__ proj) {
    __shared__ f16 Ah[128][72];   // [m][k], +8 pad
    __shared__ f16 Bh[64][72];    // [n][k], +8 pad
    const int tid = threadIdx.x;
    const int m0 = blockIdx.x * 128;
    const int n0 = blockIdx.y * 64;
    const int w  = tid >> 6;
    const int l  = tid & 63;
    const int wm = (w >> 1) * 64;   // wave m-offset
    const int wn = (w & 1) * 32;    // wave n-offset
    const int lr = l & 15;          // fragment row/col lane index
    const int lk = l >> 4;          // k-group (0..3)

    f32x4 acc[4][2];
    #pragma unroll
    for (int mi = 0; mi < 4; mi++)
        #pragma unroll
        for (int ni = 0; ni < 2; ni++) acc[mi][ni] = (f32x4){0.f, 0.f, 0.f, 0.f};

    const int srow = tid >> 4;          // 0..15 staging row
    const int sc4  = (tid & 15) * 4;    // staging col*4

    for (int k0 = 0; k0 < EMB; k0 += 64) {
        __syncthreads();   // previous iter's frag reads done before overwrite
        // stage A: 128 rows x 64 k (fp32 -> f16)
        #pragma unroll
        for (int it = 0; it < 8; it++) {
            int row = it * 16 + srow;
            float4 v = *(const float4*)(x + (size_t)(m0 + row) * EMB + k0 + sc4);
            f16x4 h = {(f16)v.x, (f16)v.y, (f16)v.z, (f16)v.w};
            *(f16x4*)&Ah[row][sc4] = h;
        }
        // stage B: 64 rows x 64 k, zero-fill beyond OP
        #pragma unroll
        for (int it = 0; it < 4; it++) {
            int row = it * 16 + srow;
            int o = n0 + row;
            float4 v = make_float4(0.f, 0.f, 0.f, 0.f);
            if (o < OP) v = *(const float4*)(W + (size_t)o * EMB + k0 + sc4);
            f16x4 h = {(f16)v.x, (f16)v.y, (f16)v.z, (f16)v.w};
            *(f16x4*)&Bh[row][sc4] = h;
        }
        __syncthreads();
        // fragments + MFMA: k-slices ks*32, lane holds 8 f16 at k=(ks*32 + lk*8)
        #pragma unroll
        for (int ks = 0; ks < 2; ks++) {
            f16x8 bfr[2];
            #pragma unroll
            for (int ni = 0; ni < 2; ni++)
                bfr[ni] = *(const f16x8*)&Bh[wn + ni * 16 + lr][ks * 32 + lk * 8];
            #pragma unroll
            for (int mi = 0; mi < 4; mi++) {
                f16x8 afr = *(const f16x8*)&Ah[wm + mi * 16 + lr][ks * 32 + lk * 8];
                #pragma unroll
                for (int ni = 0; ni < 2; ni++)
                    acc[mi][ni] = __builtin_amdgcn_mfma_f32_16x16x32_f16(afr, bfr[ni], acc[mi][ni], 0, 0, 0);
            }
        }
    }
    // epilogue: C[row=(l>>4)*4+j][col=l&15] (m89-verified), + bias
    #pragma unroll
    for (int ni = 0; ni < 2; ni++) {
        int o = n0 + wn + ni * 16 + lr;
        if (o >= OP) continue;
        float bb = bias[o];
        #pragma unroll
        for (int mi = 0; mi < 4; mi++) {
            int mrow = m0 + wm + mi * 16 + lk * 4;
            #pragma unroll
            for (int j = 0; j < 4; j++)
                proj[(size_t)(mrow + j) * OP + o] = acc[mi][ni][j] + bb;
        }
    }
}

// ---------------- K2: positional projection ----------------
// pe[h][n][d] = sum_p pos_emb[n][p] * W_pos[h*4+d][p]   (stored (H, 1023, 4))
__global__ __launch_bounds__(256) void k_pe(const float* __restrict__ pos_emb,
                                            const float* __restrict__ W_pos,
                                            float* __restrict__ pe) {
    int n  = blockIdx.x * 8 + (threadIdx.x >> 5);
    int hd = threadIdx.x & 31;
    if (n >= NREL) return;
    const float* pr = pos_emb + (size_t)n * 192;
    const float* wr = W_pos + (size_t)hd * 192;
    float s = 0.f;
    #pragma unroll
    for (int p = 0; p < 192; p += 4) {
        float4 a = *(const float4*)(pr + p);
        float4 b = *(const float4*)(wr + p);
        s = fmaf(a.x, b.x, fmaf(a.y, b.y, fmaf(a.z, b.z, fmaf(a.w, b.w, s))));
    }
    int h = hd >> 2, d = hd & 3;
    pe[((size_t)h * NREL + n) * 4 + d] = s;
}

// ---------------- K3: fused scores + rel-shift pos + mask + softmax ----------------
// One block: 16 rows of one (h,b). 4 waves, 4 rows/wave, 8 cols/lane.
__global__ __launch_bounds__(256) void k_attn(const float* __restrict__ proj,
                                              const float* __restrict__ pe,
                                              const unsigned char* __restrict__ mask,
                                              float* __restrict__ out) {
    __shared__ float  q_lds[16][32];
    __shared__ float4 p_lds[16];
    __shared__ float  pe_lds[544][4];
    __shared__ float  k_lds[2][64][36];  // double-buffered K chunk (64 rows x 32 d)
    __shared__ float  m_lds[512];        // 1.0 = masked

    const int tid = threadIdx.x;
    const int w = tid >> 6;
    const int l = tid & 63;
    const int bid  = blockIdx.x;
    const int rblk = bid & 31;
    const int hb   = bid >> 5;
    const int b = hb & 15;
    const int h = hb >> 4;
    const int i0 = rblk << 4;

    // ---- initial staging: K chunk 0, q, p, mask, pe ----
    #pragma unroll
    for (int q = 0; q < 2; q++) {
        int idx = tid + 256 * q;
        int row = idx >> 3;             // 0..63 (t for chunk 0)
        int d4  = (idx & 7) << 2;
        float4 v = *(const float4*)(proj + ((size_t)row * BATCH + b) * OP + 256 + h * DQ + d4);
        *(float4*)&k_lds[0][row][d4] = v;
    }
    if (tid < 128) {
        int row = tid >> 3;
        int d4  = (tid & 7) << 2;
        float4 v = *(const float4*)(proj + ((size_t)(i0 + row) * BATCH + b) * OP + h * DQ + d4);
        *(float4*)&q_lds[row][d4] = v;
    } else if (tid < 192) {
        int t2 = tid - 128;
        int row = t2 >> 2;
        int d = t2 & 3;
        ((float*)&p_lds[row])[d] = proj[((size_t)(i0 + row) * BATCH + b) * OP + 512 + h * DP + d];
    } else {
        int t3 = tid - 192;
        const uchar4* mb = (const uchar4*)(mask + b * SEQ);
        #pragma unroll
        for (int q = 0; q < 2; q++) {
            int j = t3 + 64 * q;
            uchar4 mv = mb[j];
            m_lds[j * 4 + 0] = mv.x ? 1.f : 0.f;
            m_lds[j * 4 + 1] = mv.y ? 1.f : 0.f;
            m_lds[j * 4 + 2] = mv.z ? 1.f : 0.f;
            m_lds[j * 4 + 3] = mv.w ? 1.f : 0.f;
        }
    }
    const int n_base = 496 - i0;   // pe window base; nn = t + 15 - di
    #pragma unroll
    for (int q = 0; q < 3; q++) {
        int nn = tid + 256 * q;
        if (nn < 544) {
            int n = n_base + nn;
            float4 v = make_float4(0.f, 0.f, 0.f, 0.f);
            if (n >= 0 && n < NREL) v = *(const float4*)(pe + ((size_t)h * NREL + n) * 4);
            *(float4*)&pe_lds[nn][0] = v;
        }
    }
    __syncthreads();

    // q,p into registers (this wave's 4 rows)
    const int di0 = w << 2;
    float4 qreg[4][8];
    float4 preg[4];
    #pragma unroll
    for (int r = 0; r < 4; r++) {
        #pragma unroll
        for (int d4 = 0; d4 < 8; d4++)
            qreg[r][d4] = *(const float4*)&q_lds[di0 + r][d4 * 4];
        preg[r] = p_lds[di0 + r];
    }

    float score[4][8];
    #pragma unroll
    for (int c = 0; c < 8; c++) {
        float4 kst[2];
        // prefetch next K chunk global->reg (latency hidden under compute)
        if (c < 7) {
            #pragma unroll
            for (int q = 0; q < 2; q++) {
                int idx = tid + 256 * q;
                int row = idx >> 3;
                int d4  = (idx & 7) << 2;
                int t = (c + 1) * 64 + row;
                kst[q] = *(const float4*)(proj + ((size_t)t * BATCH + b) * OP + 256 + h * DQ + d4);
            }
        }
        {   // compute on buffer c&1; this lane's col t = c*64 + l
            const int buf = c & 1;
            float4 kv[8];
            #pragma unroll
            for (int d4 = 0; d4 < 8; d4++)
                kv[d4] = *(const float4*)&k_lds[buf][l][d4 * 4];
            #pragma unroll
            for (int r = 0; r < 4; r++) {
                float s = 0.f;
                #pragma unroll
                for (int d4 = 0; d4 < 8; d4++) {
                    s = fmaf(qreg[r][d4].x, kv[d4].x, s);
                    s = fmaf(qreg[r][d4].y, kv[d4].y, s);
                    s = fmaf(qreg[r][d4].z, kv[d4].z, s);
                    s = fmaf(qreg[r][d4].w, kv[d4].w, s);
                }
                int nn = c * 64 + l + 15 - (di0 + r);   // rel-shift index into pe window
                float4 pv = *(const float4*)&pe_lds[nn][0];
                s = fmaf(preg[r].x, pv.x, s);
                s = fmaf(preg[r].y, pv.y, s);
                s = fmaf(preg[r].z, pv.z, s);
                s = fmaf(preg[r].w, pv.w, s);
                score[r][c] = s;
            }
        }
        if (c < 7) {
            #pragma unroll
            for (int q = 0; q < 2; q++) {
                int idx = tid + 256 * q;
                int row = idx >> 3;
                int d4  = (idx & 7) << 2;
                *(float4*)&k_lds[(c + 1) & 1][row][d4] = kst[q];
            }
            __syncthreads();
        }
    }

    // ---- mask + softmax + write ----
    #pragma unroll
    for (int r = 0; r < 4; r++) {
        const int i = i0 + di0 + r;
        float mx = -1e30f;
        #pragma unroll
        for (int c = 0; c < 8; c++) {
            float s = score[r][c];
            if (m_lds[c * 64 + l] != 0.f) s = -1000.f;
            score[r][c] = s;
            mx = fmaxf(mx, s);
        }
        #pragma unroll
        for (int off = 32; off > 0; off >>= 1)
            mx = fmaxf(mx, __shfl_xor(mx, off));
        float sum = 0.f;
        #pragma unroll
        for (int c = 0; c < 8; c++) {
            float e = __expf(score[r][c] - mx);
            score[r][c] = e;
            sum += e;
        }
        #pragma unroll
        for (int off = 32; off > 0; off >>= 1)
            sum += __shfl_xor(sum, off);
        float inv = 1.f / sum;
        float* orow = out + (((size_t)(h * BATCH + b)) * SEQ + i) * SEQ;
        #pragma unroll
        for (int c = 0; c < 8; c++)
            orow[c * 64 + l] = score[r][c] * inv;
    }
}

extern "C" void kernel_launch(void* const* d_in, const int* in_sizes, int n_in,
                              void* d_out, int out_size, void* d_ws, size_t ws_size,
                              hipStream_t stream) {
    const float* x        = (const float*)d_in[0];
    const float* pos_emb  = (const float*)d_in[1];
    const unsigned char* mask = (const unsigned char*)d_in[2];
    const float* W_in     = (const float*)d_in[3];
    const float* b_in     = (const float*)d_in[4];
    const float* W_pos    = (const float*)d_in[5];
    float* out = (float*)d_out;

    float* proj = (float*)d_ws;                       // 8192*544 fp32 = 17.0 MiB
    float* pe   = proj + (size_t)8192 * OP;           // 8*1023*4 fp32

    k_inproj_mfma<<<dim3(64, 9), 256, 0, stream>>>(x, W_in, b_in, proj);
    k_pe<<<dim3(128), 256, 0, stream>>>(pos_emb, W_pos, pe);
    k_attn<<<dim3(4096), 256, 0, stream>>>(proj, pe, mask, out);
}

// Round 7
// 202.588 us; speedup vs baseline: 1.7469x; 1.7469x over previous
//
#include <hip/hip_runtime.h>

#define SEQ   512
#define BATCH 16
#define EMB   512
#define NH    8
#define DQ    32
#define DP    4
#define OP    544     // (32+32+4)*8
#define NREL  1023    // 2*SEQ-1

typedef _Float16 f16;
typedef _Float16 f16x4 __attribute__((ext_vector_type(4)));
typedef _Float16 f16x8 __attribute__((ext_vector_type(8)));
typedef float    f32x4 __attribute__((ext_vector_type(4)));

// ---------------- K1: in_proj GEMM via fp16 MFMA ----------------
// proj[m][o] = sum_e x[m][e] * W[o][e] + bias[o];  M=8192, N=544, K=512
// BM=128, BN=64, BK=64; 256 threads = 4 waves (2x2). Reg-prefetch double buffer.
__global__ __launch_bounds__(256) void k_inproj_mfma(const float* __restrict__ x,
                                                     const float* __restrict__ W,
                                                     const float* __restrict__ bias,
                                                     float* __restrict__ proj) {
    __shared__ f16 Ah[128][72];   // [m][k], 144B stride (16B-aligned)
    __shared__ f16 Bh[64][72];    // [n][k]
    const int tid = threadIdx.x;
    const int m0 = blockIdx.x * 128;
    const int n0 = blockIdx.y * 64;
    const int w  = tid >> 6;
    const int l  = tid & 63;
    const int wm = (w >> 1) * 64;
    const int wn = (w & 1) * 32;
    const int lr = l & 15;
    const int lk = l >> 4;
    const int srow = tid >> 4;
    const int sc4  = (tid & 15) * 4;

    f32x4 acc[4][2];
    #pragma unroll
    for (int mi = 0; mi < 4; mi++)
        #pragma unroll
        for (int ni = 0; ni < 2; ni++) acc[mi][ni] = (f32x4){0.f, 0.f, 0.f, 0.f};

    float4 aReg[8];
    float4 bReg[4];
    // prefetch K-tile 0
    #pragma unroll
    for (int it = 0; it < 8; it++)
        aReg[it] = *(const float4*)(x + (size_t)(m0 + it * 16 + srow) * EMB + sc4);
    #pragma unroll
    for (int it = 0; it < 4; it++) {
        int o = n0 + it * 16 + srow;
        bReg[it] = make_float4(0.f, 0.f, 0.f, 0.f);
        if (o < OP) bReg[it] = *(const float4*)(W + (size_t)o * EMB + sc4);
    }

    for (int k0 = 0; k0 < EMB; k0 += 64) {
        #pragma unroll
        for (int it = 0; it < 8; it++) {
            f16x4 hv = {(f16)aReg[it].x, (f16)aReg[it].y, (f16)aReg[it].z, (f16)aReg[it].w};
            *(f16x4*)&Ah[it * 16 + srow][sc4] = hv;
        }
        #pragma unroll
        for (int it = 0; it < 4; it++) {
            f16x4 hv = {(f16)bReg[it].x, (f16)bReg[it].y, (f16)bReg[it].z, (f16)bReg[it].w};
            *(f16x4*)&Bh[it * 16 + srow][sc4] = hv;
        }
        __syncthreads();
        if (k0 + 64 < EMB) {   // issue next tile's loads, hidden under MFMA phase
            #pragma unroll
            for (int it = 0; it < 8; it++)
                aReg[it] = *(const float4*)(x + (size_t)(m0 + it * 16 + srow) * EMB + (k0 + 64) + sc4);
            #pragma unroll
            for (int it = 0; it < 4; it++) {
                int o = n0 + it * 16 + srow;
                bReg[it] = make_float4(0.f, 0.f, 0.f, 0.f);
                if (o < OP) bReg[it] = *(const float4*)(W + (size_t)o * EMB + (k0 + 64) + sc4);
            }
        }
        #pragma unroll
        for (int ks = 0; ks < 2; ks++) {
            f16x8 bfr[2];
            #pragma unroll
            for (int ni = 0; ni < 2; ni++)
                bfr[ni] = *(const f16x8*)&Bh[wn + ni * 16 + lr][ks * 32 + lk * 8];
            #pragma unroll
            for (int mi = 0; mi < 4; mi++) {
                f16x8 afr = *(const f16x8*)&Ah[wm + mi * 16 + lr][ks * 32 + lk * 8];
                #pragma unroll
                for (int ni = 0; ni < 2; ni++)
                    acc[mi][ni] = __builtin_amdgcn_mfma_f32_16x16x32_f16(afr, bfr[ni], acc[mi][ni], 0, 0, 0);
            }
        }
        __syncthreads();
    }
    // epilogue: C[col=lane&15 -> o][row=(lane>>4)*4+j -> m] (HW-confirmed), + bias
    #pragma unroll
    for (int ni = 0; ni < 2; ni++) {
        int o = n0 + wn + ni * 16 + lr;
        if (o >= OP) continue;
        float bb = bias[o];
        #pragma unroll
        for (int mi = 0; mi < 4; mi++) {
            int mrow = m0 + wm + mi * 16 + lk * 4;
            #pragma unroll
            for (int j = 0; j < 4; j++)
                proj[(size_t)(mrow + j) * OP + o] = acc[mi][ni][j] + bb;
        }
    }
}

// ---------------- K2: positional projection ----------------
__global__ __launch_bounds__(256) void k_pe(const float* __restrict__ pos_emb,
                                            const float* __restrict__ W_pos,
                                            float* __restrict__ pe) {
    int n  = blockIdx.x * 8 + (threadIdx.x >> 5);
    int hd = threadIdx.x & 31;
    if (n >= NREL) return;
    const float* pr = pos_emb + (size_t)n * 192;
    const float* wr = W_pos + (size_t)hd * 192;
    float s = 0.f;
    #pragma unroll
    for (int p = 0; p < 192; p += 4) {
        float4 a = *(const float4*)(pr + p);
        float4 b = *(const float4*)(wr + p);
        s = fmaf(a.x, b.x, fmaf(a.y, b.y, fmaf(a.z, b.z, fmaf(a.w, b.w, s))));
    }
    int h = hd >> 2, d = hd & 3;
    pe[((size_t)h * NREL + n) * 4 + d] = s;
}

// ---------------- K3: MFMA QK^T (swapped) + rel-shift pos + mask + softmax ----------------
// Block: 64 rows of one (h,b); 4 waves x 16 rows. S^T = K·Q^T so each lane
// owns one q-row (col=lane&15) and 4 consecutive t per chunk -> float4 stores,
// row-reduce via shfl_xor(16/32) only.
__global__ __launch_bounds__(256, 2) void k_attn_mfma(const float* __restrict__ proj,
                                                      const float* __restrict__ pe,
                                                      const unsigned char* __restrict__ mask,
                                                      float* __restrict__ out) {
    __shared__ f16    Kh[512][40];   // 80B stride: 16B-aligned frags, ~uniform banks
    __shared__ f16    Qh[64][40];
    __shared__ float4 pe_win[576];   // rel-pos window: nn = t - iloc + 63
    __shared__ float4 p_lds[64];
    __shared__ float  m_lds[512];

    const int tid = threadIdx.x;
    const int w  = tid >> 6;
    const int l  = tid & 63;
    const int lr = l & 15;
    const int lk = l >> 4;
    const int bid  = blockIdx.x;
    const int rblk = bid & 7;
    const int hb   = bid >> 3;
    const int b = hb & 15;
    const int h = hb >> 4;
    const int i0 = rblk << 6;

    // ---- stage K (512x32), Q (64x32) as f16; p, mask, pe window ----
    #pragma unroll
    for (int it = 0; it < 16; it++) {
        int idx = tid + 256 * it;
        int row = idx >> 3;
        int c4  = (idx & 7) << 2;
        float4 v = *(const float4*)(proj + ((size_t)row * BATCH + b) * OP + 256 + h * DQ + c4);
        f16x4 hv = {(f16)v.x, (f16)v.y, (f16)v.z, (f16)v.w};
        *(f16x4*)&Kh[row][c4] = hv;
    }
    #pragma unroll
    for (int it = 0; it < 2; it++) {
        int idx = tid + 256 * it;
        int row = idx >> 3;
        int c4  = (idx & 7) << 2;
        float4 v = *(const float4*)(proj + ((size_t)(i0 + row) * BATCH + b) * OP + h * DQ + c4);
        f16x4 hv = {(f16)v.x, (f16)v.y, (f16)v.z, (f16)v.w};
        *(f16x4*)&Qh[row][c4] = hv;
    }
    if (tid < 64)
        p_lds[tid] = *(const float4*)(proj + ((size_t)(i0 + tid) * BATCH + b) * OP + 512 + h * DP);
    if (tid >= 64 && tid < 192) {
        int t4 = tid - 64;
        uchar4 mv = ((const uchar4*)(mask + b * SEQ))[t4];
        m_lds[t4 * 4 + 0] = mv.x ? 1.f : 0.f;
        m_lds[t4 * 4 + 1] = mv.y ? 1.f : 0.f;
        m_lds[t4 * 4 + 2] = mv.z ? 1.f : 0.f;
        m_lds[t4 * 4 + 3] = mv.w ? 1.f : 0.f;
    }
    {   // pe_win[nn] = pe[h][448 - i0 + nn], nn in [0,575); always in range
        const int n_base = 448 - i0;
        #pragma unroll
        for (int q = 0; q < 3; q++) {
            int nn = tid + 256 * q;
            if (nn < 575)
                pe_win[nn] = *(const float4*)(pe + ((size_t)h * NREL + n_base + nn) * 4);
        }
    }
    __syncthreads();

    // ---- QK^T: 32 chunks of 16 keys; acc[c][j] = S[i0+iloc][c*16+lk*4+j] ----
    const int iloc = w * 16 + lr;
    const f16x8 qf = *(const f16x8*)&Qh[iloc][lk * 8];
    const float4 p4 = p_lds[iloc];
    f32x4 acc[32];
    const f32x4 zero = (f32x4){0.f, 0.f, 0.f, 0.f};
    #pragma unroll
    for (int c = 0; c < 32; c++) {
        f16x8 kf = *(const f16x8*)&Kh[c * 16 + lr][lk * 8];
        acc[c] = __builtin_amdgcn_mfma_f32_16x16x32_f16(kf, qf, zero, 0, 0, 0);
    }

    // ---- add rel-shift positional scores + mask ----
    #pragma unroll
    for (int c = 0; c < 32; c++) {
        const int tb = c * 16 + lk * 4;
        #pragma unroll
        for (int j = 0; j < 4; j++) {
            const int t = tb + j;
            float4 pv = pe_win[t - iloc + 63];
            float s = acc[c][j];
            s = fmaf(p4.x, pv.x, s);
            s = fmaf(p4.y, pv.y, s);
            s = fmaf(p4.z, pv.z, s);
            s = fmaf(p4.w, pv.w, s);
            acc[c][j] = (m_lds[t] != 0.f) ? -1000.f : s;
        }
    }

    // ---- softmax (row i lives in lanes {lr, lr^16, lr^32, lr^48}) ----
    float mx = -1e30f;
    #pragma unroll
    for (int c = 0; c < 32; c++)
        #pragma unroll
        for (int j = 0; j < 4; j++) mx = fmaxf(mx, acc[c][j]);
    mx = fmaxf(mx, __shfl_xor(mx, 16));
    mx = fmaxf(mx, __shfl_xor(mx, 32));
    float sum = 0.f;
    #pragma unroll
    for (int c = 0; c < 32; c++)
        #pragma unroll
        for (int j = 0; j < 4; j++) {
            float e = __expf(acc[c][j] - mx);
            acc[c][j] = e;
            sum += e;
        }
    sum += __shfl_xor(sum, 16);
    sum += __shfl_xor(sum, 32);
    const float inv = 1.f / sum;

    // ---- scaled store: float4 of consecutive t ----
    float* orow = out + (((size_t)(h * BATCH + b)) * SEQ + i0 + iloc) * SEQ;
    #pragma unroll
    for (int c = 0; c < 32; c++) {
        float4 v = make_float4(acc[c][0] * inv, acc[c][1] * inv,
                               acc[c][2] * inv, acc[c][3] * inv);
        *(float4*)(orow + c * 16 + lk * 4) = v;
    }
}

extern "C" void kernel_launch(void* const* d_in, const int* in_sizes, int n_in,
                              void* d_out, int out_size, void* d_ws, size_t ws_size,
                              hipStream_t stream) {
    const float* x        = (const float*)d_in[0];
    const float* pos_emb  = (const float*)d_in[1];
    const unsigned char* mask = (const unsigned char*)d_in[2];
    const float* W_in     = (const float*)d_in[3];
    const float* b_in     = (const float*)d_in[4];
    const float* W_pos    = (const float*)d_in[5];
    float* out = (float*)d_out;

    float* proj = (float*)d_ws;                       // 8192*544 fp32 = 17.0 MiB
    float* pe   = proj + (size_t)8192 * OP;           // 8*1023*4 fp32

    k_inproj_mfma<<<dim3(64, 9), 256, 0, stream>>>(x, W_in, b_in, proj);
    k_pe<<<dim3(128), 256, 0, stream>>>(pos_emb, W_pos, pe);
    k_attn_mfma<<<dim3(1024), 256, 0, stream>>>(proj, pe, mask, out);
}

// Round 11
// 194.140 us; speedup vs baseline: 1.8230x; 1.0435x over previous
//
#include <hip/hip_runtime.h>

#define SEQ   512
#define BATCH 16
#define EMB   512
#define NH    8
#define DQ    32
#define DP    4
#define OP    544     // (32+32+4)*8
#define NREL  1023    // 2*SEQ-1

typedef _Float16 f16;
typedef _Float16 f16x8 __attribute__((ext_vector_type(8)));
typedef float    f32x4 __attribute__((ext_vector_type(4)));

#define NX   (SEQ * BATCH * EMB)          // 4194304 x elems
#define NW   (OP * EMB)                   // 278528 W elems
#define N8   ((NX + NW) / 8)              // 559104 groups of 8

// ---------------- K0: one-shot f32 -> f16 conversion of x and W ----------------
__global__ __launch_bounds__(256) void k_cvt(const float* __restrict__ x,
                                             const float* __restrict__ W,
                                             f16* __restrict__ x_h,
                                             f16* __restrict__ W_h) {
    int gid = blockIdx.x * 256 + threadIdx.x;
    if (gid >= N8) return;
    size_t g8 = (size_t)gid * 8;
    const float* src;
    f16* dst;
    if (g8 < NX) { src = x + g8; dst = x_h + g8; }
    else         { src = W + (g8 - NX); dst = W_h + (g8 - NX); }
    float4 a = *(const float4*)src;
    float4 b = *(const float4*)(src + 4);
    f16x8 h = {(f16)a.x, (f16)a.y, (f16)a.z, (f16)a.w,
               (f16)b.x, (f16)b.y, (f16)b.z, (f16)b.w};
    *(f16x8*)dst = h;
}

// ---------------- K1: in_proj GEMM (f16 in, f16 q/k + f32 p out) ----------------
// BM=64, BN=64, BK=64; 1152 blocks; 4 waves (2x2), 32x32 per wave.
// q/k cols (o<512) stored f16 to qk_h[8192][512]; p cols f32 to p_f[8192][32].
__global__ __launch_bounds__(256, 4) void k_inproj2(const f16* __restrict__ x_h,
                                                    const f16* __restrict__ W_h,
                                                    const float* __restrict__ bias,
                                                    f16* __restrict__ qk_h,
                                                    float* __restrict__ p_f) {
    __shared__ f16 Ah[64][72];   // [m][k], 144B stride -> balanced b128 frags
    __shared__ f16 Bh[64][72];   // [n][k]
    const int tid = threadIdx.x;
    const int m0 = blockIdx.x * 64;
    const int n0 = blockIdx.y * 64;
    const int w  = tid >> 6;
    const int l  = tid & 63;
    const int wm = (w >> 1) * 32;
    const int wn = (w & 1) * 32;
    const int lr = l & 15;
    const int lk = l >> 4;

    f32x4 acc[2][2];
    #pragma unroll
    for (int mi = 0; mi < 2; mi++)
        #pragma unroll
        for (int ni = 0; ni < 2; ni++) acc[mi][ni] = (f32x4){0.f, 0.f, 0.f, 0.f};

    f16x8 aReg[2], bReg[2];
    // prefetch K-tile 0: rows idx>>3, cols (idx&7)*8 (16B per lane)
    #pragma unroll
    for (int it = 0; it < 2; it++) {
        int idx = tid + 256 * it;
        int row = idx >> 3, c8 = (idx & 7) * 8;
        aReg[it] = *(const f16x8*)(x_h + (size_t)(m0 + row) * EMB + c8);
        int o = n0 + row;
        bReg[it] = (f16x8){0,0,0,0,0,0,0,0};
        if (o < OP) bReg[it] = *(const f16x8*)(W_h + (size_t)o * EMB + c8);
    }

    for (int k0 = 0; k0 < EMB; k0 += 64) {
        #pragma unroll
        for (int it = 0; it < 2; it++) {
            int idx = tid + 256 * it;
            int row = idx >> 3, c8 = (idx & 7) * 8;
            *(f16x8*)&Ah[row][c8] = aReg[it];
            *(f16x8*)&Bh[row][c8] = bReg[it];
        }
        __syncthreads();
        if (k0 + 64 < EMB) {   // prefetch next tile under MFMA phase
            #pragma unroll
            for (int it = 0; it < 2; it++) {
                int idx = tid + 256 * it;
                int row = idx >> 3, c8 = (idx & 7) * 8;
                aReg[it] = *(const f16x8*)(x_h + (size_t)(m0 + row) * EMB + (k0 + 64) + c8);
                int o = n0 + row;
                bReg[it] = (f16x8){0,0,0,0,0,0,0,0};
                if (o < OP) bReg[it] = *(const f16x8*)(W_h + (size_t)o * EMB + (k0 + 64) + c8);
            }
        }
        #pragma unroll
        for (int ks = 0; ks < 2; ks++) {
            f16x8 bfr[2];
            #pragma unroll
            for (int ni = 0; ni < 2; ni++)
                bfr[ni] = *(const f16x8*)&Bh[wn + ni * 16 + lr][ks * 32 + lk * 8];
            #pragma unroll
            for (int mi = 0; mi < 2; mi++) {
                f16x8 afr = *(const f16x8*)&Ah[wm + mi * 16 + lr][ks * 32 + lk * 8];
                #pragma unroll
                for (int ni = 0; ni < 2; ni++)
                    acc[mi][ni] = __builtin_amdgcn_mfma_f32_16x16x32_f16(afr, bfr[ni], acc[mi][ni], 0, 0, 0);
            }
        }
        __syncthreads();
    }
    // epilogue: col o = n0+wn+ni*16+lr; row m = m0+wm+mi*16+lk*4+j
    #pragma unroll
    for (int ni = 0; ni < 2; ni++) {
        int o = n0 + wn + ni * 16 + lr;
        if (o >= OP) continue;
        float bb = bias[o];
        #pragma unroll
        for (int mi = 0; mi < 2; mi++) {
            int mrow = m0 + wm + mi * 16 + lk * 4;
            #pragma unroll
            for (int j = 0; j < 4; j++) {
                float v = acc[mi][ni][j] + bb;
                if (o < 512) qk_h[(size_t)(mrow + j) * 512 + o] = (f16)v;
                else         p_f[(size_t)(mrow + j) * 32 + (o - 512)] = v;
            }
        }
    }
}

// ---------------- K2: positional projection ----------------
__global__ __launch_bounds__(256) void k_pe(const float* __restrict__ pos_emb,
                                            const float* __restrict__ W_pos,
                                            float* __restrict__ pe) {
    int n  = blockIdx.x * 8 + (threadIdx.x >> 5);
    int hd = threadIdx.x & 31;
    if (n >= NREL) return;
    const float* pr = pos_emb + (size_t)n * 192;
    const float* wr = W_pos + (size_t)hd * 192;
    float s = 0.f;
    #pragma unroll
    for (int p = 0; p < 192; p += 4) {
        float4 a = *(const float4*)(pr + p);
        float4 b = *(const float4*)(wr + p);
        s = fmaf(a.x, b.x, fmaf(a.y, b.y, fmaf(a.z, b.z, fmaf(a.w, b.w, s))));
    }
    int h = hd >> 2, d = hd & 3;
    pe[((size_t)h * NREL + n) * 4 + d] = s;
}

// ---------------- K3: MFMA QK^T (swapped) + rel-shift pos + mask + softmax ----------------
// Block: 64 q-rows of one (h,b); f16 staging from qk_h; XCD-swizzled blockIdx.
__global__ __launch_bounds__(256, 2) void k_attn2(const f16* __restrict__ qk_h,
                                                  const float* __restrict__ p_f,
                                                  const float* __restrict__ pe,
                                                  const unsigned char* __restrict__ mask,
                                                  float* __restrict__ out) {
    __shared__ f16    Kh[512][40];   // 80B stride: aligned b128 frags, balanced banks
    __shared__ f16    Qh[64][40];
    __shared__ float4 pe_win[576];
    __shared__ float4 p_lds[64];
    __shared__ float  m_lds[512];

    const int tid = threadIdx.x;
    const int w  = tid >> 6;
    const int l  = tid & 63;
    const int lr = l & 15;
    const int lk = l >> 4;
    // XCD swizzle: 8 rblk-blocks of one (h,b) land on the same XCD (1024 % 8 == 0)
    const int wg   = (blockIdx.x & 7) * 128 + (blockIdx.x >> 3);
    const int rblk = wg & 7;
    const int hb   = wg >> 3;
    const int b = hb & 15;
    const int h = hb >> 4;
    const int i0 = rblk << 6;

    // ---- stage K (512x32 f16), Q (64x32 f16), p, mask, pe window ----
    #pragma unroll
    for (int it = 0; it < 8; it++) {
        int idx = tid + 256 * it;
        int row = idx >> 2, c8 = (idx & 3) * 8;
        f16x8 v = *(const f16x8*)(qk_h + ((size_t)row * BATCH + b) * 512 + 256 + h * DQ + c8);
        *(f16x8*)&Kh[row][c8] = v;
    }
    {
        int row = tid >> 2, c8 = (tid & 3) * 8;
        f16x8 v = *(const f16x8*)(qk_h + ((size_t)(i0 + row) * BATCH + b) * 512 + h * DQ + c8);
        *(f16x8*)&Qh[row][c8] = v;
    }
    if (tid < 64)
        p_lds[tid] = *(const float4*)(p_f + ((size_t)(i0 + tid) * BATCH + b) * 32 + h * DP);
    if (tid >= 64 && tid < 192) {
        int t4 = tid - 64;
        uchar4 mv = ((const uchar4*)(mask + b * SEQ))[t4];
        m_lds[t4 * 4 + 0] = mv.x ? 1.f : 0.f;
        m_lds[t4 * 4 + 1] = mv.y ? 1.f : 0.f;
        m_lds[t4 * 4 + 2] = mv.z ? 1.f : 0.f;
        m_lds[t4 * 4 + 3] = mv.w ? 1.f : 0.f;
    }
    {   // pe_win[nn] = pe[h][448 - i0 + nn], nn in [0,575); always in range
        const int n_base = 448 - i0;
        #pragma unroll
        for (int q = 0; q < 3; q++) {
            int nn = tid + 256 * q;
            if (nn < 575)
                pe_win[nn] = *(const float4*)(pe + ((size_t)h * NREL + n_base + nn) * 4);
        }
    }
    __syncthreads();

    // ---- QK^T: acc[c][j] = S[i0+w*16+lr][c*16+lk*4+j] ----
    const int iloc = w * 16 + lr;
    const f16x8 qf = *(const f16x8*)&Qh[iloc][lk * 8];
    const float4 p4 = p_lds[iloc];
    f32x4 acc[32];
    const f32x4 zero = (f32x4){0.f, 0.f, 0.f, 0.f};
    #pragma unroll
    for (int c = 0; c < 32; c++) {
        f16x8 kf = *(const f16x8*)&Kh[c * 16 + lr][lk * 8];
        acc[c] = __builtin_amdgcn_mfma_f32_16x16x32_f16(kf, qf, zero, 0, 0, 0);
    }

    // ---- rel-shift positional scores + mask ----
    #pragma unroll
    for (int c = 0; c < 32; c++) {
        const int tb = c * 16 + lk * 4;
        #pragma unroll
        for (int j = 0; j < 4; j++) {
            const int t = tb + j;
            float4 pv = pe_win[t - iloc + 63];
            float s = acc[c][j];
            s = fmaf(p4.x, pv.x, s);
            s = fmaf(p4.y, pv.y, s);
            s = fmaf(p4.z, pv.z, s);
            s = fmaf(p4.w, pv.w, s);
            acc[c][j] = (m_lds[t] != 0.f) ? -1000.f : s;
        }
    }

    // ---- softmax (row lives in lanes {lr, lr^16, lr^32, lr^48}) ----
    float mx = -1e30f;
    #pragma unroll
    for (int c = 0; c < 32; c++)
        #pragma unroll
        for (int j = 0; j < 4; j++) mx = fmaxf(mx, acc[c][j]);
    mx = fmaxf(mx, __shfl_xor(mx, 16));
    mx = fmaxf(mx, __shfl_xor(mx, 32));
    float sum = 0.f;
    #pragma unroll
    for (int c = 0; c < 32; c++)
        #pragma unroll
        for (int j = 0; j < 4; j++) {
            float e = __expf(acc[c][j] - mx);
            acc[c][j] = e;
            sum += e;
        }
    sum += __shfl_xor(sum, 16);
    sum += __shfl_xor(sum, 32);
    const float inv = 1.f / sum;

    float* orow = out + (((size_t)(h * BATCH + b)) * SEQ + i0 + iloc) * SEQ;
    #pragma unroll
    for (int c = 0; c < 32; c++) {
        float4 v = make_float4(acc[c][0] * inv, acc[c][1] * inv,
                               acc[c][2] * inv, acc[c][3] * inv);
        *(float4*)(orow + c * 16 + lk * 4) = v;
    }
}

extern "C" void kernel_launch(void* const* d_in, const int* in_sizes, int n_in,
                              void* d_out, int out_size, void* d_ws, size_t ws_size,
                              hipStream_t stream) {
    const float* x        = (const float*)d_in[0];
    const float* pos_emb  = (const float*)d_in[1];
    const unsigned char* mask = (const unsigned char*)d_in[2];
    const float* W_in     = (const float*)d_in[3];
    const float* b_in     = (const float*)d_in[4];
    const float* W_pos    = (const float*)d_in[5];
    float* out = (float*)d_out;

    // ws layout (16B-aligned chunks)
    f16*   x_h  = (f16*)d_ws;                          // 4194304 f16
    f16*   W_h  = x_h + NX;                            // 278528 f16
    f16*   qk_h = W_h + NW;                            // 8192*512 f16
    float* p_f  = (float*)(qk_h + (size_t)8192 * 512); // 8192*32 f32
    float* pe   = p_f + (size_t)8192 * 32;             // 8*1023*4 f32

    k_cvt<<<dim3((N8 + 255) / 256), 256, 0, stream>>>(x, W_in, x_h, W_h);
    k_inproj2<<<dim3(128, 9), 256, 0, stream>>>(x_h, W_h, b_in, qk_h, p_f);
    k_pe<<<dim3(128), 256, 0, stream>>>(pos_emb, W_pos, pe);
    k_attn2<<<dim3(1024), 256, 0, stream>>>(qk_h, p_f, pe, mask, out);
}